// Round 4
// baseline (178.445 us; speedup 1.0000x reference)
//
#include <hip/hip_runtime.h>

typedef unsigned short u16;
typedef __attribute__((ext_vector_type(8))) __bf16 bf16x8;
typedef __attribute__((ext_vector_type(4))) float f32x4;
typedef __attribute__((ext_vector_type(4))) int   i32x4;

#define NLQ 32768          // N*Lq
#define QN  (NLQ*256)      // query elements
#define WPN (384*256)      // proj weight elements
#define WON (256*256)      // out weight elements
#define FM4 6806528        // fm float4 count = 13294*8*256/4

static __device__ __forceinline__ u16 f2bf(float f) {
    unsigned u = __float_as_uint(f);
    return (u16)((u + 0x7fffu + ((u >> 16) & 1u)) >> 16);   // RNE
}

// ---------------------------------------------------------------------------
// Convert: query -> qbf[(n*4096+lq)*256+c] bf16 ; W_off|W_attn -> wtp[j][k] ;
// W_out -> wto[j][k] (transposed so MFMA B-frags load contiguous k).
// ---------------------------------------------------------------------------
__global__ __launch_bounds__(256) void convert_kernel(
    const float* __restrict__ q,
    const float* __restrict__ W_off, const float* __restrict__ W_attn,
    const float* __restrict__ W_out,
    u16* __restrict__ qbf, u16* __restrict__ wtp, u16* __restrict__ wto)
{
    size_t i = (size_t)blockIdx.x * 256 + threadIdx.x;
    if (i < QN) {
        size_t gq = i >> 8, c = i & 255;
        size_t lq = gq & 4095, n = gq >> 12;
        qbf[i] = f2bf(q[(lq * 8 + n) * 256 + c]);
    } else if (i < QN + WPN) {
        size_t i2 = i - QN;
        int j = (int)(i2 >> 8), k = (int)(i2 & 255);
        float v = (j < 256) ? W_off[k * 256 + j] : W_attn[k * 128 + (j - 256)];
        wtp[i2] = f2bf(v);
    } else {
        size_t i3 = i - QN - WPN;
        int j = (int)(i3 >> 8), k = (int)(i3 & 255);
        wto[i3] = f2bf(W_out[k * 256 + j]);
    }
}

// ---------------------------------------------------------------------------
// Feature-map f32 -> bf16 (straight streaming convert, float4 -> ushort4).
// Launched AFTER proj_gemm because the bf16 buffer overlays qbf.
// ---------------------------------------------------------------------------
__global__ __launch_bounds__(256) void fmconv_kernel(
    const float4* __restrict__ fm, ushort4* __restrict__ fmb)
{
    int i = blockIdx.x * 256 + threadIdx.x;
    float4 v = fm[i];
    ushort4 r;
    r.x = f2bf(v.x); r.y = f2bf(v.y); r.z = f2bf(v.z); r.w = f2bf(v.w);
    fmb[i] = r;
}

// ---------------------------------------------------------------------------
// MFMA GEMM: C(32768 x 384) = qbf(32768 x 256) * Wt^T ; raw proj + bias.
// ---------------------------------------------------------------------------
__global__ __launch_bounds__(256) void proj_gemm(
    const u16* __restrict__ A, const u16* __restrict__ Bt,
    const float* __restrict__ b_off, const float* __restrict__ b_attn,
    float* __restrict__ C)
{
    const int t = threadIdx.x;
    const int wid = t >> 6, lane = t & 63;
    const int lr = lane & 15, lk = lane >> 4;
    const int mrow = blockIdx.x * 128 + (wid >> 1) * 64;
    const int ncol = blockIdx.y * 128 + (wid & 1) * 64;
    const int kO = lk * 8;

    f32x4 acc[4][4] = {};
#pragma unroll
    for (int kk = 0; kk < 8; ++kk) {
        bf16x8 a[4], b[4];
#pragma unroll
        for (int mi = 0; mi < 4; ++mi)
            a[mi] = *(const bf16x8*)(A + (size_t)(mrow + mi * 16 + lr) * 256 + kk * 32 + kO);
#pragma unroll
        for (int ni = 0; ni < 4; ++ni)
            b[ni] = *(const bf16x8*)(Bt + (size_t)(ncol + ni * 16 + lr) * 256 + kk * 32 + kO);
#pragma unroll
        for (int mi = 0; mi < 4; ++mi)
#pragma unroll
            for (int ni = 0; ni < 4; ++ni)
                acc[mi][ni] = __builtin_amdgcn_mfma_f32_16x16x32_bf16(a[mi], b[ni], acc[mi][ni], 0, 0, 0);
    }

#pragma unroll
    for (int ni = 0; ni < 4; ++ni) {
        int gcol = ncol + ni * 16 + lr;
        float bias = (gcol < 256) ? b_off[gcol] : b_attn[gcol - 256];
#pragma unroll
        for (int mi = 0; mi < 4; ++mi) {
            f32x4 v = acc[mi][ni];
#pragma unroll
            for (int r = 0; r < 4; ++r)
                C[(size_t)(mrow + mi * 16 + lk * 4 + r) * 384 + gcol] = v[r] + bias;
        }
    }
}

// ---------------------------------------------------------------------------
// Fused softmax + loc + bilinear gather (bf16 feature maps).
// Prologue (t<128): softmax, sampling locs, clamped corner offsets (units of
// 8 B) + validity*attention-premultiplied weights into LDS.
// Main: head h = t>>5, 4 groups x 8 lanes; lane reads uint2 (4 bf16 ch) per
// corner; all 16 loads issued before the unpack+FMA pass.
// ---------------------------------------------------------------------------
__global__ __launch_bounds__(256) void sample_kernel(
    const u16* __restrict__ fmb,
    const float* __restrict__ proj,
    const float* __restrict__ refp,
    u16* __restrict__ mid)
{
    __shared__ i32x4 loff[128];
    __shared__ f32x4 lwv[128];
    const int gq = blockIdx.x;
    const int n = gq >> 12;
    const int t = threadIdx.x;

    if (t < 128) {
        const int lp = t & 15, l = lp >> 2;
        float lg = proj[(size_t)gq * 384 + 256 + t];
        float m = lg;
#pragma unroll
        for (int msk = 1; msk < 16; msk <<= 1) m = fmaxf(m, __shfl_xor(m, msk));
        float e = __expf(lg - m);
        float s = e;
#pragma unroll
        for (int msk = 1; msk < 16; msk <<= 1) s += __shfl_xor(s, msk);
        float a = e / s;

        float ox = proj[(size_t)gq * 384 + 2 * t];
        float oy = proj[(size_t)gq * 384 + 2 * t + 1];
        int   Sl = (l == 0) ? 100 : (l == 1) ? 50 : (l == 2) ? 25 : 13;
        int   lb = (l == 0) ? 0 : (l == 1) ? 10000 : (l == 2) ? 12500 : 13125;
        float Sf = (float)Sl;
        float rx = refp[((size_t)gq * 4 + l) * 2 + 0];
        float ry = refp[((size_t)gq * 4 + l) * 2 + 1];
        float px = rx * Sf + ox - 0.5f;
        float py = ry * Sf + oy - 0.5f;
        float x0f = floorf(px), y0f = floorf(py);
        float wx = px - x0f, wy = py - y0f;
        int x0 = (int)x0f, y0 = (int)y0f;
        bool xv0 = (unsigned)x0 < (unsigned)Sl;
        bool xv1 = (unsigned)(x0 + 1) < (unsigned)Sl;
        bool yv0 = (unsigned)y0 < (unsigned)Sl;
        bool yv1 = (unsigned)(y0 + 1) < (unsigned)Sl;
        int x0c = min(max(x0, 0), Sl - 1), x1c = min(max(x0 + 1, 0), Sl - 1);
        int y0c = min(max(y0, 0), Sl - 1), y1c = min(max(y0 + 1, 0), Sl - 1);
        // offsets in units of 8 B (uint2): per-pos stride = 8*256*2B = 512 u
        int r0 = (lb + y0c * Sl) * 512, r1 = (lb + y1c * Sl) * 512;
        i32x4 o; f32x4 w;
        o.x = r0 + x0c * 512; o.y = r0 + x1c * 512;
        o.z = r1 + x0c * 512; o.w = r1 + x1c * 512;
        w.x = (xv0 && yv0) ? a * (1.f - wx) * (1.f - wy) : 0.f;
        w.y = (xv1 && yv0) ? a * wx * (1.f - wy) : 0.f;
        w.z = (xv0 && yv1) ? a * (1.f - wx) * wy : 0.f;
        w.w = (xv1 && yv1) ? a * wx * wy : 0.f;
        loff[t] = o;
        lwv[t] = w;
    }
    __syncthreads();

    const int h = t >> 5, ll = t & 31, g = ll >> 3, cq = ll & 7;
    // base: n*256ch + h*32ch + cq*4ch, in uint2 (4ch) units
    const uint2* __restrict__ fmc = (const uint2*)fmb + (size_t)n * 64 + h * 8 + cq;

    uint2 v[4][4];
    f32x4 w[4];
#pragma unroll
    for (int pi = 0; pi < 4; ++pi) {
        int idx = h * 16 + pi * 4 + g;
        i32x4 o = loff[idx];
        w[pi] = lwv[idx];
        v[pi][0] = fmc[o.x];
        v[pi][1] = fmc[o.y];
        v[pi][2] = fmc[o.z];
        v[pi][3] = fmc[o.w];
    }

    float acc0 = 0.f, acc1 = 0.f, acc2 = 0.f, acc3 = 0.f;
#pragma unroll
    for (int pi = 0; pi < 4; ++pi) {
#pragma unroll
        for (int cn = 0; cn < 4; ++cn) {
            float wt = w[pi][cn];
            uint2 u = v[pi][cn];
            acc0 += wt * __uint_as_float(u.x << 16);
            acc1 += wt * __uint_as_float(u.x & 0xFFFF0000u);
            acc2 += wt * __uint_as_float(u.y << 16);
            acc3 += wt * __uint_as_float(u.y & 0xFFFF0000u);
        }
    }
    // reduce across the 4 point-groups (lane bits 3 and 4)
    acc0 += __shfl_xor(acc0, 8);  acc1 += __shfl_xor(acc1, 8);
    acc2 += __shfl_xor(acc2, 8);  acc3 += __shfl_xor(acc3, 8);
    acc0 += __shfl_xor(acc0, 16); acc1 += __shfl_xor(acc1, 16);
    acc2 += __shfl_xor(acc2, 16); acc3 += __shfl_xor(acc3, 16);

    if (ll < 8) {
        ushort4 r;
        r.x = f2bf(acc0); r.y = f2bf(acc1);
        r.z = f2bf(acc2); r.w = f2bf(acc3);
        ((ushort4*)mid)[(size_t)gq * 64 + h * 8 + cq] = r;
    }
}

// ---------------------------------------------------------------------------
// MFMA GEMM: out = mid(32768 x 256, bf16) * W_out^T + b_out, transposed write.
// ---------------------------------------------------------------------------
__global__ __launch_bounds__(256) void out_gemm(
    const u16* __restrict__ A, const u16* __restrict__ Bt,
    const float* __restrict__ b_out,
    float* __restrict__ out)
{
    const int t = threadIdx.x;
    const int wid = t >> 6, lane = t & 63;
    const int lr = lane & 15, lk = lane >> 4;
    const int mrow = blockIdx.x * 128 + (wid >> 1) * 64;
    const int ncol = blockIdx.y * 128 + (wid & 1) * 64;
    const int kO = lk * 8;

    f32x4 acc[4][4] = {};
#pragma unroll
    for (int kk = 0; kk < 8; ++kk) {
        bf16x8 a[4], b[4];
#pragma unroll
        for (int mi = 0; mi < 4; ++mi)
            a[mi] = *(const bf16x8*)(A + (size_t)(mrow + mi * 16 + lr) * 256 + kk * 32 + kO);
#pragma unroll
        for (int ni = 0; ni < 4; ++ni)
            b[ni] = *(const bf16x8*)(Bt + (size_t)(ncol + ni * 16 + lr) * 256 + kk * 32 + kO);
#pragma unroll
        for (int mi = 0; mi < 4; ++mi)
#pragma unroll
            for (int ni = 0; ni < 4; ++ni)
                acc[mi][ni] = __builtin_amdgcn_mfma_f32_16x16x32_bf16(a[mi], b[ni], acc[mi][ni], 0, 0, 0);
    }

#pragma unroll
    for (int ni = 0; ni < 4; ++ni) {
        int gcol = ncol + ni * 16 + lr;
        float bias = b_out[gcol];
#pragma unroll
        for (int mi = 0; mi < 4; ++mi) {
            f32x4 v = acc[mi][ni];
#pragma unroll
            for (int r = 0; r < 4; ++r) {
                int grow = mrow + mi * 16 + lk * 4 + r;
                int nn = grow >> 12, lq = grow & 4095;
                out[(size_t)(lq * 8 + nn) * 256 + gcol] = v[r] + bias;
            }
        }
    }
}

extern "C" void kernel_launch(void* const* d_in, const int* in_sizes, int n_in,
                              void* d_out, int out_size, void* d_ws, size_t ws_size,
                              hipStream_t stream) {
    const float* query  = (const float*)d_in[0];
    const float* refp   = (const float*)d_in[1];
    const float* fm     = (const float*)d_in[2];
    const float* W_off  = (const float*)d_in[4];
    const float* b_off  = (const float*)d_in[5];
    const float* W_attn = (const float*)d_in[6];
    const float* b_attn = (const float*)d_in[7];
    const float* W_out  = (const float*)d_in[8];
    const float* b_out  = (const float*)d_in[9];
    float* out = (float*)d_out;

    // workspace layout (peak ~122 MB); fmb overlays qbf (qbf dead after proj)
    float* ws_proj = (float*)d_ws;                        // 32768*384 f32 (50.3 MB)
    u16*   wtp     = (u16*)(ws_proj + (size_t)NLQ * 384); // 384*256 bf16
    u16*   wto     = wtp + (size_t)WPN;                   // 256*256 bf16
    u16*   mid     = wto + (size_t)WON;                   // 32768*256 bf16 (16.8 MB)
    u16*   fmb     = mid + (size_t)NLQ * 256;             // 13294*2048 bf16 (54.5 MB)
    u16*   qbf     = fmb;                                 // 32768*256 bf16 (16.8 MB), dies at proj

    const int TOT = QN + WPN + WON;                       // 8552448 = 33408*256
    convert_kernel<<<TOT / 256, 256, 0, stream>>>(query, W_off, W_attn, W_out,
                                                  qbf, wtp, wto);
    proj_gemm<<<dim3(256, 3), 256, 0, stream>>>(qbf, wtp, b_off, b_attn, ws_proj);
    fmconv_kernel<<<FM4 / 256, 256, 0, stream>>>((const float4*)fm, (ushort4*)fmb);
    sample_kernel<<<NLQ, 256, 0, stream>>>(fmb, ws_proj, refp, mid);
    out_gemm<<<dim3(256, 2), 256, 0, stream>>>(mid, wto, b_out, out);
}

// Round 5
// 171.881 us; speedup vs baseline: 1.0382x; 1.0382x over previous
//
#include <hip/hip_runtime.h>

typedef unsigned short u16;
typedef __attribute__((ext_vector_type(8))) __bf16 bf16x8;
typedef __attribute__((ext_vector_type(4))) float f32x4;
typedef __attribute__((ext_vector_type(4))) int   i32x4;

#define NLQ 32768          // N*Lq
#define WPN (384*256)      // proj weight elements
#define WON (256*256)      // out weight elements
#define FM4 6806528        // fm float4 count = 13294*8*256/4 = 6647*1024

static __device__ __forceinline__ u16 f2bf(float f) {
    unsigned u = __float_as_uint(f);
    return (u16)((u + 0x7fffu + ((u >> 16) & 1u)) >> 16);   // RNE
}

// ---------------------------------------------------------------------------
// Prep: fm f32 -> bf16 (same (pos,n,c) layout), 4 float4/thread for MLP;
// W_off|W_attn -> wtp[j][k], W_out -> wto[j][k] (transposed) in the tail blocks.
// ---------------------------------------------------------------------------
__global__ __launch_bounds__(256) void prep_kernel(
    const float4* __restrict__ fm, ushort4* __restrict__ fmb,
    const float* __restrict__ W_off, const float* __restrict__ W_attn,
    const float* __restrict__ W_out,
    u16* __restrict__ wtp, u16* __restrict__ wto)
{
    const int b = blockIdx.x, t = threadIdx.x;
    if (b < 6647) {
        const int base = b * 1024 + t;
        float4 v[4];
#pragma unroll
        for (int j = 0; j < 4; ++j) v[j] = fm[base + j * 256];
#pragma unroll
        for (int j = 0; j < 4; ++j) {
            ushort4 r;
            r.x = f2bf(v[j].x); r.y = f2bf(v[j].y);
            r.z = f2bf(v[j].z); r.w = f2bf(v[j].w);
            fmb[base + j * 256] = r;
        }
    } else {
        const int wi = (b - 6647) * 256 + t;
        if (wi < WPN) {
            int j = wi >> 8, k = wi & 255;
            float v = (j < 256) ? W_off[k * 256 + j] : W_attn[k * 128 + (j - 256)];
            wtp[wi] = f2bf(v);
        } else {
            int wi2 = wi - WPN;
            int j = wi2 >> 8, k = wi2 & 255;
            wto[wi2] = f2bf(W_out[k * 256 + j]);
        }
    }
}

// ---------------------------------------------------------------------------
// MFMA GEMM: C(32768 x 384) = query(f32, transposed rows, cvt on the fly)
//            * Wt^T + bias.  Block 128x128, 4 waves, 4x4 16x16x32 frags/wave.
// ---------------------------------------------------------------------------
__global__ __launch_bounds__(256) void proj_gemm(
    const float* __restrict__ query, const u16* __restrict__ Bt,
    const float* __restrict__ b_off, const float* __restrict__ b_attn,
    float* __restrict__ C)
{
    const int t = threadIdx.x;
    const int wid = t >> 6, lane = t & 63;
    const int lr = lane & 15, lk = lane >> 4;
    const int mrow = blockIdx.x * 128 + (wid >> 1) * 64;
    const int ncol = blockIdx.y * 128 + (wid & 1) * 64;
    const int kO = lk * 8;

    const float* qrow[4];
#pragma unroll
    for (int mi = 0; mi < 4; ++mi) {
        int gq = mrow + mi * 16 + lr;
        qrow[mi] = query + (size_t)((gq & 4095) * 8 + (gq >> 12)) * 256;
    }

    f32x4 acc[4][4] = {};
#pragma unroll
    for (int kk = 0; kk < 8; ++kk) {
        bf16x8 a[4], b[4];
#pragma unroll
        for (int mi = 0; mi < 4; ++mi) {
            f32x4 lo = *(const f32x4*)(qrow[mi] + kk * 32 + kO);
            f32x4 hi = *(const f32x4*)(qrow[mi] + kk * 32 + kO + 4);
#pragma unroll
            for (int j = 0; j < 4; ++j) {
                a[mi][j]     = (__bf16)lo[j];
                a[mi][4 + j] = (__bf16)hi[j];
            }
        }
#pragma unroll
        for (int ni = 0; ni < 4; ++ni)
            b[ni] = *(const bf16x8*)(Bt + (size_t)(ncol + ni * 16 + lr) * 256 + kk * 32 + kO);
#pragma unroll
        for (int mi = 0; mi < 4; ++mi)
#pragma unroll
            for (int ni = 0; ni < 4; ++ni)
                acc[mi][ni] = __builtin_amdgcn_mfma_f32_16x16x32_bf16(a[mi], b[ni], acc[mi][ni], 0, 0, 0);
    }

#pragma unroll
    for (int ni = 0; ni < 4; ++ni) {
        int gcol = ncol + ni * 16 + lr;
        float bias = (gcol < 256) ? b_off[gcol] : b_attn[gcol - 256];
#pragma unroll
        for (int mi = 0; mi < 4; ++mi) {
            f32x4 v = acc[mi][ni];
#pragma unroll
            for (int r = 0; r < 4; ++r)
                C[(size_t)(mrow + mi * 16 + lk * 4 + r) * 384 + gcol] = v[r] + bias;
        }
    }
}

// ---------------------------------------------------------------------------
// Fused softmax + loc + bilinear gather (bf16 fm). 2 queries per block.
// Prologue: all 256 threads -> (ql = t>>7, point = t&127): softmax (16-lane
// shfl groups), clamped corner BYTE offsets + premultiplied weights to LDS.
// Main: per query-half (128 thr): head = tq>>4, 2 groups x 8 lanes; lane reads
// uint2 (4 bf16 ch) per corner; 16 loads in flight per 4-point batch.
// ---------------------------------------------------------------------------
__global__ __launch_bounds__(256) void sample_kernel(
    const u16* __restrict__ fmb,
    const float* __restrict__ proj,
    const float* __restrict__ refp,
    u16* __restrict__ mid)
{
    __shared__ i32x4 loff[256];
    __shared__ f32x4 lwv[256];
    const int t = threadIdx.x;
    const int ql = t >> 7, pt = t & 127;
    const int gq = blockIdx.x * 2 + ql;
    const int n = gq >> 12;

    {
        const int lp = pt & 15, l = lp >> 2;
        float lg = proj[(size_t)gq * 384 + 256 + pt];
        float m = lg;
#pragma unroll
        for (int msk = 1; msk < 16; msk <<= 1) m = fmaxf(m, __shfl_xor(m, msk));
        float e = __expf(lg - m);
        float s = e;
#pragma unroll
        for (int msk = 1; msk < 16; msk <<= 1) s += __shfl_xor(s, msk);
        float a = e / s;

        float ox = proj[(size_t)gq * 384 + 2 * pt];
        float oy = proj[(size_t)gq * 384 + 2 * pt + 1];
        int   Sl = (l == 0) ? 100 : (l == 1) ? 50 : (l == 2) ? 25 : 13;
        int   lb = (l == 0) ? 0 : (l == 1) ? 10000 : (l == 2) ? 12500 : 13125;
        float Sf = (float)Sl;
        float rx = refp[((size_t)gq * 4 + l) * 2 + 0];
        float ry = refp[((size_t)gq * 4 + l) * 2 + 1];
        float px = rx * Sf + ox - 0.5f;
        float py = ry * Sf + oy - 0.5f;
        float x0f = floorf(px), y0f = floorf(py);
        float wx = px - x0f, wy = py - y0f;
        int x0 = (int)x0f, y0 = (int)y0f;
        bool xv0 = (unsigned)x0 < (unsigned)Sl;
        bool xv1 = (unsigned)(x0 + 1) < (unsigned)Sl;
        bool yv0 = (unsigned)y0 < (unsigned)Sl;
        bool yv1 = (unsigned)(y0 + 1) < (unsigned)Sl;
        int x0c = min(max(x0, 0), Sl - 1), x1c = min(max(x0 + 1, 0), Sl - 1);
        int y0c = min(max(y0, 0), Sl - 1), y1c = min(max(y0 + 1, 0), Sl - 1);
        // BYTE offsets; per-pos stride = 8*256*2B = 4096
        int r0 = (lb + y0c * Sl) << 12, r1 = (lb + y1c * Sl) << 12;
        i32x4 o; f32x4 w;
        o.x = r0 + (x0c << 12); o.y = r0 + (x1c << 12);
        o.z = r1 + (x0c << 12); o.w = r1 + (x1c << 12);
        w.x = (xv0 && yv0) ? a * (1.f - wx) * (1.f - wy) : 0.f;
        w.y = (xv1 && yv0) ? a * wx * (1.f - wy) : 0.f;
        w.z = (xv0 && yv1) ? a * (1.f - wx) * wy : 0.f;
        w.w = (xv1 && yv1) ? a * wx * wy : 0.f;
        loff[t] = o;
        lwv[t] = w;
    }
    __syncthreads();

    const int h = pt >> 4, ll = pt & 15, g = ll >> 3, cq = ll & 7;
    const uint boff = (uint)(n * 512 + h * 64 + cq * 8);
    const char* __restrict__ fb = (const char*)fmb;

    float acc0 = 0.f, acc1 = 0.f, acc2 = 0.f, acc3 = 0.f;
#pragma unroll
    for (int bi = 0; bi < 2; ++bi) {
        uint2 v[4][4];
        f32x4 w[4];
#pragma unroll
        for (int pi = 0; pi < 4; ++pi) {
            int idx = ql * 128 + h * 16 + g * 8 + bi * 4 + pi;
            i32x4 o = loff[idx];
            w[pi] = lwv[idx];
            v[pi][0] = *(const uint2*)(fb + (boff + (uint)o.x));
            v[pi][1] = *(const uint2*)(fb + (boff + (uint)o.y));
            v[pi][2] = *(const uint2*)(fb + (boff + (uint)o.z));
            v[pi][3] = *(const uint2*)(fb + (boff + (uint)o.w));
        }
#pragma unroll
        for (int pi = 0; pi < 4; ++pi) {
#pragma unroll
            for (int cn = 0; cn < 4; ++cn) {
                float wt = w[pi][cn];
                uint2 u = v[pi][cn];
                acc0 += wt * __uint_as_float(u.x << 16);
                acc1 += wt * __uint_as_float(u.x & 0xFFFF0000u);
                acc2 += wt * __uint_as_float(u.y << 16);
                acc3 += wt * __uint_as_float(u.y & 0xFFFF0000u);
            }
        }
    }
    // combine the two 8-point groups (lane bit 3)
    acc0 += __shfl_xor(acc0, 8);  acc1 += __shfl_xor(acc1, 8);
    acc2 += __shfl_xor(acc2, 8);  acc3 += __shfl_xor(acc3, 8);

    if (ll < 8) {
        ushort4 r;
        r.x = f2bf(acc0); r.y = f2bf(acc1);
        r.z = f2bf(acc2); r.w = f2bf(acc3);
        ((ushort4*)mid)[(size_t)gq * 64 + h * 8 + cq] = r;
    }
}

// ---------------------------------------------------------------------------
// MFMA GEMM: out = mid(32768 x 256, bf16) * W_out^T + b_out, transposed write.
// ---------------------------------------------------------------------------
__global__ __launch_bounds__(256) void out_gemm(
    const u16* __restrict__ A, const u16* __restrict__ Bt,
    const float* __restrict__ b_out,
    float* __restrict__ out)
{
    const int t = threadIdx.x;
    const int wid = t >> 6, lane = t & 63;
    const int lr = lane & 15, lk = lane >> 4;
    const int mrow = blockIdx.x * 128 + (wid >> 1) * 64;
    const int ncol = blockIdx.y * 128 + (wid & 1) * 64;
    const int kO = lk * 8;

    f32x4 acc[4][4] = {};
#pragma unroll
    for (int kk = 0; kk < 8; ++kk) {
        bf16x8 a[4], b[4];
#pragma unroll
        for (int mi = 0; mi < 4; ++mi)
            a[mi] = *(const bf16x8*)(A + (size_t)(mrow + mi * 16 + lr) * 256 + kk * 32 + kO);
#pragma unroll
        for (int ni = 0; ni < 4; ++ni)
            b[ni] = *(const bf16x8*)(Bt + (size_t)(ncol + ni * 16 + lr) * 256 + kk * 32 + kO);
#pragma unroll
        for (int mi = 0; mi < 4; ++mi)
#pragma unroll
            for (int ni = 0; ni < 4; ++ni)
                acc[mi][ni] = __builtin_amdgcn_mfma_f32_16x16x32_bf16(a[mi], b[ni], acc[mi][ni], 0, 0, 0);
    }

#pragma unroll
    for (int ni = 0; ni < 4; ++ni) {
        int gcol = ncol + ni * 16 + lr;
        float bias = b_out[gcol];
#pragma unroll
        for (int mi = 0; mi < 4; ++mi) {
            f32x4 v = acc[mi][ni];
#pragma unroll
            for (int r = 0; r < 4; ++r) {
                int grow = mrow + mi * 16 + lk * 4 + r;
                int nn = grow >> 12, lq = grow & 4095;
                out[(size_t)(lq * 8 + nn) * 256 + gcol] = v[r] + bias;
            }
        }
    }
}

extern "C" void kernel_launch(void* const* d_in, const int* in_sizes, int n_in,
                              void* d_out, int out_size, void* d_ws, size_t ws_size,
                              hipStream_t stream) {
    const float* query  = (const float*)d_in[0];
    const float* refp   = (const float*)d_in[1];
    const float* fm     = (const float*)d_in[2];
    const float* W_off  = (const float*)d_in[4];
    const float* b_off  = (const float*)d_in[5];
    const float* W_attn = (const float*)d_in[6];
    const float* b_attn = (const float*)d_in[7];
    const float* W_out  = (const float*)d_in[8];
    const float* b_out  = (const float*)d_in[9];
    float* out = (float*)d_out;

    // workspace (~122 MB)
    float* ws_proj = (float*)d_ws;                        // 32768*384 f32 (50.3 MB)
    u16*   wtp     = (u16*)(ws_proj + (size_t)NLQ * 384); // 384*256 bf16
    u16*   wto     = wtp + (size_t)WPN;                   // 256*256 bf16
    u16*   mid     = wto + (size_t)WON;                   // 32768*256 bf16 (16.8 MB)
    u16*   fmb     = mid + (size_t)NLQ * 256;             // 13294*2048 bf16 (54.5 MB)

    prep_kernel<<<6647 + 640, 256, 0, stream>>>((const float4*)fm, (ushort4*)fmb,
                                                W_off, W_attn, W_out, wtp, wto);
    proj_gemm<<<dim3(256, 3), 256, 0, stream>>>(query, wtp, b_off, b_attn, ws_proj);
    sample_kernel<<<NLQ / 2, 256, 0, stream>>>(fmb, ws_proj, refp, mid);
    out_gemm<<<dim3(256, 2), 256, 0, stream>>>(mid, wto, b_out, out);
}

// Round 6
// 161.327 us; speedup vs baseline: 1.1061x; 1.0654x over previous
//
#include <hip/hip_runtime.h>

typedef unsigned short u16;
typedef __attribute__((ext_vector_type(8))) __bf16 bf16x8;
typedef __attribute__((ext_vector_type(4))) float f32x4;
typedef __attribute__((ext_vector_type(4))) int   i32x4;

#define NLQ 32768          // N*Lq
#define WPN (384*256)      // proj weight elements
#define WON (256*256)      // out weight elements
#define FMU 3403264        // fm 32B-units = 13294*8*256/8

static __device__ __forceinline__ u16 f2bf(float f) {
    unsigned u = __float_as_uint(f);
    return (u16)((u + 0x7fffu + ((u >> 16) & 1u)) >> 16);   // RNE
}
static __device__ __forceinline__ uint pk2(float lo, float hi) {
    return (uint)f2bf(lo) | ((uint)f2bf(hi) << 16);
}

// ---------------------------------------------------------------------------
// Weight transpose+convert only (proj_gemm's sole dependency): ~3 us.
// wtp[j][k] <- [W_off | W_attn], wto[j][k] <- W_out.
// ---------------------------------------------------------------------------
__global__ __launch_bounds__(256) void wconv_kernel(
    const float* __restrict__ W_off, const float* __restrict__ W_attn,
    const float* __restrict__ W_out,
    u16* __restrict__ wtp, u16* __restrict__ wto)
{
    const int wi = blockIdx.x * 256 + threadIdx.x;
    if (wi < WPN) {
        int j = wi >> 8, k = wi & 255;
        float v = (j < 256) ? W_off[k * 256 + j] : W_attn[k * 128 + (j - 256)];
        wtp[wi] = f2bf(v);
    } else {
        int wi2 = wi - WPN;
        int j = wi2 >> 8, k = wi2 & 255;
        wto[wi2] = f2bf(W_out[k * 256 + j]);
    }
}

// ---------------------------------------------------------------------------
// Fused: blocks [0,768) = proj GEMM (C = query*Wt^T + bias, on-the-fly bf16
// cvt of query); blocks [768, 4092) = fm f32->bf16 stream (2xfloat4 -> uint4
// units, 4 units/thread). Memory-bound stream overlaps compute-bound MFMA.
// ---------------------------------------------------------------------------
__global__ __launch_bounds__(256) void fused_kernel(
    const float* __restrict__ query, const u16* __restrict__ Bt,
    const float* __restrict__ b_off, const float* __restrict__ b_attn,
    float* __restrict__ C,
    const float4* __restrict__ fm, uint4* __restrict__ fmb)
{
    const int bx = blockIdx.x, t = threadIdx.x;
    if (bx >= 768) {
        // ---- fm conversion: unit = 32B in (2 float4), 16B out (8 bf16)
        const int ub = (bx - 768) * 1024 + t;
#pragma unroll
        for (int j = 0; j < 4; ++j) {
            int u = ub + j * 256;
            if (u < FMU) {
                float4 lo = fm[2 * u], hi = fm[2 * u + 1];
                uint4 r;
                r.x = pk2(lo.x, lo.y); r.y = pk2(lo.z, lo.w);
                r.z = pk2(hi.x, hi.y); r.w = pk2(hi.z, hi.w);
                fmb[u] = r;
            }
        }
        return;
    }
    // ---- proj GEMM block: 128x128 tile, 4 waves, 4x4 16x16x32 frags
    const int wid = t >> 6, lane = t & 63;
    const int lr = lane & 15, lk = lane >> 4;
    const int mrow = (bx & 255) * 128 + (wid >> 1) * 64;
    const int ncol = (bx >> 8) * 128 + (wid & 1) * 64;
    const int kO = lk * 8;

    const float* qrow[4];
#pragma unroll
    for (int mi = 0; mi < 4; ++mi) {
        int gq = mrow + mi * 16 + lr;
        qrow[mi] = query + (size_t)((gq & 4095) * 8 + (gq >> 12)) * 256;
    }

    f32x4 acc[4][4] = {};
#pragma unroll
    for (int kk = 0; kk < 8; ++kk) {
        bf16x8 a[4], b[4];
#pragma unroll
        for (int mi = 0; mi < 4; ++mi) {
            f32x4 lo = *(const f32x4*)(qrow[mi] + kk * 32 + kO);
            f32x4 hi = *(const f32x4*)(qrow[mi] + kk * 32 + kO + 4);
#pragma unroll
            for (int j = 0; j < 4; ++j) {
                a[mi][j]     = (__bf16)lo[j];
                a[mi][4 + j] = (__bf16)hi[j];
            }
        }
#pragma unroll
        for (int ni = 0; ni < 4; ++ni)
            b[ni] = *(const bf16x8*)(Bt + (size_t)(ncol + ni * 16 + lr) * 256 + kk * 32 + kO);
#pragma unroll
        for (int mi = 0; mi < 4; ++mi)
#pragma unroll
            for (int ni = 0; ni < 4; ++ni)
                acc[mi][ni] = __builtin_amdgcn_mfma_f32_16x16x32_bf16(a[mi], b[ni], acc[mi][ni], 0, 0, 0);
    }

#pragma unroll
    for (int ni = 0; ni < 4; ++ni) {
        int gcol = ncol + ni * 16 + lr;
        float bias = (gcol < 256) ? b_off[gcol] : b_attn[gcol - 256];
#pragma unroll
        for (int mi = 0; mi < 4; ++mi) {
            f32x4 v = acc[mi][ni];
#pragma unroll
            for (int r = 0; r < 4; ++r)
                C[(size_t)(mrow + mi * 16 + lk * 4 + r) * 384 + gcol] = v[r] + bias;
        }
    }
}

// ---------------------------------------------------------------------------
// Fused softmax + loc + bilinear gather (bf16 fm). 2 queries per block.
// Prologue: 256 threads -> (ql = t>>7, point = t&127): softmax (16-lane shfl),
// clamped corner BYTE offsets + premultiplied weights -> LDS.
// Main: 16 lanes/head = 4 point-groups x 4 lanes; lane reads uint4 (8 bf16 ch)
// per corner -> 16B requests, 16 loads/thread total.
// ---------------------------------------------------------------------------
__global__ __launch_bounds__(256) void sample_kernel(
    const u16* __restrict__ fmb,
    const float* __restrict__ proj,
    const float* __restrict__ refp,
    u16* __restrict__ mid)
{
    __shared__ i32x4 loff[256];
    __shared__ f32x4 lwv[256];
    const int t = threadIdx.x;
    const int ql = t >> 7, pt = t & 127;
    const int gq = blockIdx.x * 2 + ql;
    const int n = gq >> 12;

    {
        const int lp = pt & 15, l = lp >> 2;
        float lg = proj[(size_t)gq * 384 + 256 + pt];
        float m = lg;
#pragma unroll
        for (int msk = 1; msk < 16; msk <<= 1) m = fmaxf(m, __shfl_xor(m, msk));
        float e = __expf(lg - m);
        float s = e;
#pragma unroll
        for (int msk = 1; msk < 16; msk <<= 1) s += __shfl_xor(s, msk);
        float a = e / s;

        float ox = proj[(size_t)gq * 384 + 2 * pt];
        float oy = proj[(size_t)gq * 384 + 2 * pt + 1];
        int   Sl = (l == 0) ? 100 : (l == 1) ? 50 : (l == 2) ? 25 : 13;
        int   lb = (l == 0) ? 0 : (l == 1) ? 10000 : (l == 2) ? 12500 : 13125;
        float Sf = (float)Sl;
        float rx = refp[((size_t)gq * 4 + l) * 2 + 0];
        float ry = refp[((size_t)gq * 4 + l) * 2 + 1];
        float px = rx * Sf + ox - 0.5f;
        float py = ry * Sf + oy - 0.5f;
        float x0f = floorf(px), y0f = floorf(py);
        float wx = px - x0f, wy = py - y0f;
        int x0 = (int)x0f, y0 = (int)y0f;
        bool xv0 = (unsigned)x0 < (unsigned)Sl;
        bool xv1 = (unsigned)(x0 + 1) < (unsigned)Sl;
        bool yv0 = (unsigned)y0 < (unsigned)Sl;
        bool yv1 = (unsigned)(y0 + 1) < (unsigned)Sl;
        int x0c = min(max(x0, 0), Sl - 1), x1c = min(max(x0 + 1, 0), Sl - 1);
        int y0c = min(max(y0, 0), Sl - 1), y1c = min(max(y0 + 1, 0), Sl - 1);
        // BYTE offsets; per-pos stride = 8*256*2B = 4096
        int r0 = (lb + y0c * Sl) << 12, r1 = (lb + y1c * Sl) << 12;
        i32x4 o; f32x4 w;
        o.x = r0 + (x0c << 12); o.y = r0 + (x1c << 12);
        o.z = r1 + (x0c << 12); o.w = r1 + (x1c << 12);
        w.x = (xv0 && yv0) ? a * (1.f - wx) * (1.f - wy) : 0.f;
        w.y = (xv1 && yv0) ? a * wx * (1.f - wy) : 0.f;
        w.z = (xv0 && yv1) ? a * (1.f - wx) * wy : 0.f;
        w.w = (xv1 && yv1) ? a * wx * wy : 0.f;
        loff[t] = o;
        lwv[t] = w;
    }
    __syncthreads();

    const int h = pt >> 4, ll = pt & 15, g2 = ll >> 2, cl = ll & 3;
    const uint boff = (uint)(n * 512 + h * 64 + cl * 16);
    const char* __restrict__ fb = (const char*)fmb;

    float a0 = 0.f, a1 = 0.f, a2 = 0.f, a3 = 0.f;
    float a4 = 0.f, a5 = 0.f, a6 = 0.f, a7 = 0.f;
#pragma unroll
    for (int pi = 0; pi < 4; ++pi) {
        int idx = ql * 128 + h * 16 + g2 * 4 + pi;
        i32x4 o = loff[idx];
        f32x4 w = lwv[idx];
        uint4 v0 = *(const uint4*)(fb + (boff + (uint)o.x));
        uint4 v1 = *(const uint4*)(fb + (boff + (uint)o.y));
        uint4 v2 = *(const uint4*)(fb + (boff + (uint)o.z));
        uint4 v3 = *(const uint4*)(fb + (boff + (uint)o.w));
#define ACC8(u, wt)                                        \
        a0 += wt * __uint_as_float(u.x << 16);             \
        a1 += wt * __uint_as_float(u.x & 0xFFFF0000u);     \
        a2 += wt * __uint_as_float(u.y << 16);             \
        a3 += wt * __uint_as_float(u.y & 0xFFFF0000u);     \
        a4 += wt * __uint_as_float(u.z << 16);             \
        a5 += wt * __uint_as_float(u.z & 0xFFFF0000u);     \
        a6 += wt * __uint_as_float(u.w << 16);             \
        a7 += wt * __uint_as_float(u.w & 0xFFFF0000u);
        ACC8(v0, w.x) ACC8(v1, w.y) ACC8(v2, w.z) ACC8(v3, w.w)
#undef ACC8
    }
    // reduce across the 4 point-groups (lane bits 2 and 3)
#pragma unroll
    for (int msk = 4; msk <= 8; msk <<= 1) {
        a0 += __shfl_xor(a0, msk); a1 += __shfl_xor(a1, msk);
        a2 += __shfl_xor(a2, msk); a3 += __shfl_xor(a3, msk);
        a4 += __shfl_xor(a4, msk); a5 += __shfl_xor(a5, msk);
        a6 += __shfl_xor(a6, msk); a7 += __shfl_xor(a7, msk);
    }

    if (ll < 4) {
        uint4 r;
        r.x = pk2(a0, a1); r.y = pk2(a2, a3);
        r.z = pk2(a4, a5); r.w = pk2(a6, a7);
        ((uint4*)mid)[(size_t)gq * 32 + h * 4 + cl] = r;
    }
}

// ---------------------------------------------------------------------------
// MFMA GEMM: out = mid(32768 x 256, bf16) * W_out^T + b_out, transposed write.
// ---------------------------------------------------------------------------
__global__ __launch_bounds__(256) void out_gemm(
    const u16* __restrict__ A, const u16* __restrict__ Bt,
    const float* __restrict__ b_out,
    float* __restrict__ out)
{
    const int t = threadIdx.x;
    const int wid = t >> 6, lane = t & 63;
    const int lr = lane & 15, lk = lane >> 4;
    const int mrow = blockIdx.x * 128 + (wid >> 1) * 64;
    const int ncol = blockIdx.y * 128 + (wid & 1) * 64;
    const int kO = lk * 8;

    f32x4 acc[4][4] = {};
#pragma unroll
    for (int kk = 0; kk < 8; ++kk) {
        bf16x8 a[4], b[4];
#pragma unroll
        for (int mi = 0; mi < 4; ++mi)
            a[mi] = *(const bf16x8*)(A + (size_t)(mrow + mi * 16 + lr) * 256 + kk * 32 + kO);
#pragma unroll
        for (int ni = 0; ni < 4; ++ni)
            b[ni] = *(const bf16x8*)(Bt + (size_t)(ncol + ni * 16 + lr) * 256 + kk * 32 + kO);
#pragma unroll
        for (int mi = 0; mi < 4; ++mi)
#pragma unroll
            for (int ni = 0; ni < 4; ++ni)
                acc[mi][ni] = __builtin_amdgcn_mfma_f32_16x16x32_bf16(a[mi], b[ni], acc[mi][ni], 0, 0, 0);
    }

#pragma unroll
    for (int ni = 0; ni < 4; ++ni) {
        int gcol = ncol + ni * 16 + lr;
        float bias = b_out[gcol];
#pragma unroll
        for (int mi = 0; mi < 4; ++mi) {
            f32x4 v = acc[mi][ni];
#pragma unroll
            for (int r = 0; r < 4; ++r) {
                int grow = mrow + mi * 16 + lk * 4 + r;
                int nn = grow >> 12, lq = grow & 4095;
                out[(size_t)(lq * 8 + nn) * 256 + gcol] = v[r] + bias;
            }
        }
    }
}

extern "C" void kernel_launch(void* const* d_in, const int* in_sizes, int n_in,
                              void* d_out, int out_size, void* d_ws, size_t ws_size,
                              hipStream_t stream) {
    const float* query  = (const float*)d_in[0];
    const float* refp   = (const float*)d_in[1];
    const float* fm     = (const float*)d_in[2];
    const float* W_off  = (const float*)d_in[4];
    const float* b_off  = (const float*)d_in[5];
    const float* W_attn = (const float*)d_in[6];
    const float* b_attn = (const float*)d_in[7];
    const float* W_out  = (const float*)d_in[8];
    const float* b_out  = (const float*)d_in[9];
    float* out = (float*)d_out;

    // workspace (~122 MB)
    float* ws_proj = (float*)d_ws;                        // 32768*384 f32 (50.3 MB)
    u16*   wtp     = (u16*)(ws_proj + (size_t)NLQ * 384); // 384*256 bf16
    u16*   wto     = wtp + (size_t)WPN;                   // 256*256 bf16
    u16*   mid     = wto + (size_t)WON;                   // 32768*256 bf16 (16.8 MB)
    u16*   fmb     = mid + (size_t)NLQ * 256;             // 13294*2048 bf16 (54.5 MB)

    wconv_kernel<<<640, 256, 0, stream>>>(W_off, W_attn, W_out, wtp, wto);
    fused_kernel<<<768 + 3324, 256, 0, stream>>>(query, wtp, b_off, b_attn,
                                                 ws_proj, (const float4*)fm,
                                                 (uint4*)fmb);
    sample_kernel<<<NLQ / 2, 256, 0, stream>>>(fmb, ws_proj, refp, mid);
    out_gemm<<<dim3(256, 2), 256, 0, stream>>>(mid, wto, b_out, out);
}